// Round 2
// baseline (374.871 us; speedup 1.0000x reference)
//
#include <hip/hip_runtime.h>
#include <cstdint>
#include <cstring>

// ---------------------------------------------------------------------------
// LinearBNNoise: x[65536,784] -> Linear(784,48) -> BN -> +noise(key 1234) -> ReLU
//                -> Linear(48,24) -> BN -> +noise(key 5678) -> ReLU -> Linear(24,10)
// Noise reproduces JAX threefry2x32 in PARTITIONABLE mode (default since 0.4.36):
//   split (foldlike): key_i = threefry(key, (0, i))  (both words, unXORed)
//   random_bits(32):  bits1 ^ bits2 of threefry(key, (hi, lo) of 64-bit flat idx)
//   uniform: bitcast(bits>>9 | 0x3F800000) - 1 -> [0,1)
//   normal: sqrt(2) * erfinv(u), u = max(lo, f*2+lo), lo = nextafter(-1,0);
//           XLA ErfInv32 (Giles) polynomial.
// ---------------------------------------------------------------------------

constexpr int MROWS = 65536;
constexpr int KDIM  = 784;
constexpr int F1 = 48, F2 = 24, F3 = 10;

// ---------------- threefry2x32 (20 rounds) ----------------
__device__ __forceinline__ uint32_t rotl32(uint32_t v, int r) {
  return (v << r) | (v >> (32 - r));
}

// returns XOR of both output words of threefry2x32(key=(k0,k1), counts=(0, ctr))
__device__ __forceinline__ uint32_t tf_mix(uint32_t k0, uint32_t k1, uint32_t ctr) {
  uint32_t ks2 = k0 ^ k1 ^ 0x1BD11BDAu;
  uint32_t x0 = k0;        // c0 = 0 -> x0 = 0 + k0
  uint32_t x1 = ctr + k1;
#define TFR(r) { x0 += x1; x1 = rotl32(x1, r); x1 ^= x0; }
  TFR(13) TFR(15) TFR(26) TFR(6)
  x0 += k1;  x1 += ks2 + 1u;
  TFR(17) TFR(29) TFR(16) TFR(24)
  x0 += ks2; x1 += k0 + 2u;
  TFR(13) TFR(15) TFR(26) TFR(6)
  x0 += k0;  x1 += k1 + 3u;
  TFR(17) TFR(29) TFR(16) TFR(24)
  x0 += k1;  x1 += ks2 + 4u;
  TFR(13) TFR(15) TFR(26) TFR(6)
  x0 += ks2; x1 += k0 + 5u;
#undef TFR
  return x0 ^ x1;
}

// XLA ErfInv (f32): Giles' polynomial, exactly XLA's coefficients
__device__ __forceinline__ float erfinv_f32(float x) {
  float w = -log1pf(-x * x);
  float p;
  if (w < 5.0f) {
    w = w - 2.5f;
    p = 2.81022636e-08f;
    p = fmaf(p, w, 3.43273939e-07f);
    p = fmaf(p, w, -3.5233877e-06f);
    p = fmaf(p, w, -4.39150654e-06f);
    p = fmaf(p, w, 0.00021858087f);
    p = fmaf(p, w, -0.00125372503f);
    p = fmaf(p, w, -0.00417768164f);
    p = fmaf(p, w, 0.246640727f);
    p = fmaf(p, w, 1.50140941f);
  } else {
    w = sqrtf(w) - 3.0f;
    p = -0.000200214257f;
    p = fmaf(p, w, 0.000100950558f);
    p = fmaf(p, w, 0.00134934322f);
    p = fmaf(p, w, -0.00367342844f);
    p = fmaf(p, w, 0.00573950773f);
    p = fmaf(p, w, -0.0076224613f);
    p = fmaf(p, w, 0.00943887047f);
    p = fmaf(p, w, 1.00167406f);
    p = fmaf(p, w, 2.83297682f);
  }
  return p * x;
}

// standard normal sample at flat index ctr, JAX-normal semantics
__device__ __forceinline__ float noise_normal(uint32_t k0, uint32_t k1, uint32_t ctr) {
  uint32_t bits = tf_mix(k0, k1, ctr);
  float f = __uint_as_float((bits >> 9) | 0x3f800000u) - 1.0f; // [0,1)
  const float lo = -0.99999994f;                               // nextafter(-1,0)
  float u = fmaxf(lo, f * 2.0f + lo);                          // hi-lo == 2.0f in fp32
  return 1.41421356f * erfinv_f32(u);                          // fp32(sqrt(2))
}

// ---------------- Kernel A: GEMM1 + per-feature stats ----------------
// C[128 x 48] block tile, BK=16, per-thread 4x6, register prefetch pipeline.
__global__ __launch_bounds__(256) void k_gemm1(
    const float* __restrict__ x, const float* __restrict__ w1,
    const float* __restrict__ b1, float* __restrict__ h1,
    float* __restrict__ fsum, float* __restrict__ fssq) {
  __shared__ __align__(16) float xs[16][128];   // [k][row]
  __shared__ __align__(16) float wl[16][48];    // [k][col]
  __shared__ float red[2][32][48];

  const int t = threadIdx.x;
  const int rowbase = blockIdx.x * 128;
  const int tr = t & 31, tc = t >> 5;
  const int r0 = tr * 4, c0 = tc * 6;

  float acc[4][6];
#pragma unroll
  for (int i = 0; i < 4; ++i)
#pragma unroll
    for (int j = 0; j < 6; ++j) acc[i][j] = 0.f;

  const int lrow = t >> 1;           // 0..127
  const int lk   = (t & 1) * 8;      // 0 or 8
  const float* xg = x + (size_t)(rowbase + lrow) * KDIM + lk;
  const int wf = t >> 2;             // 0..63, active < 48
  const int wk = (t & 3) * 4;
  const float* wg = w1 + (size_t)wf * KDIM + wk;

  float4 nx0 = *(const float4*)(xg);
  float4 nx1 = *(const float4*)(xg + 4);
  float4 nw  = make_float4(0.f, 0.f, 0.f, 0.f);
  if (wf < F1) nw = *(const float4*)(wg);

  for (int kb = 0; kb < KDIM; kb += 16) {
    xs[lk + 0][lrow] = nx0.x; xs[lk + 1][lrow] = nx0.y;
    xs[lk + 2][lrow] = nx0.z; xs[lk + 3][lrow] = nx0.w;
    xs[lk + 4][lrow] = nx1.x; xs[lk + 5][lrow] = nx1.y;
    xs[lk + 6][lrow] = nx1.z; xs[lk + 7][lrow] = nx1.w;
    if (wf < F1) {
      wl[wk + 0][wf] = nw.x; wl[wk + 1][wf] = nw.y;
      wl[wk + 2][wf] = nw.z; wl[wk + 3][wf] = nw.w;
    }
    __syncthreads();
    if (kb + 16 < KDIM) {  // prefetch next chunk during compute
      nx0 = *(const float4*)(xg + kb + 16);
      nx1 = *(const float4*)(xg + kb + 20);
      if (wf < F1) nw = *(const float4*)(wg + kb + 16);
    }
#pragma unroll
    for (int k = 0; k < 16; ++k) {
      float4 xq = *(const float4*)&xs[k][r0];
      float2 wa = *(const float2*)&wl[k][c0];
      float2 wb = *(const float2*)&wl[k][c0 + 2];
      float2 wc = *(const float2*)&wl[k][c0 + 4];
      float xv[4] = {xq.x, xq.y, xq.z, xq.w};
      float wv[6] = {wa.x, wa.y, wb.x, wb.y, wc.x, wc.y};
#pragma unroll
      for (int i = 0; i < 4; ++i)
#pragma unroll
        for (int j = 0; j < 6; ++j)
          acc[i][j] = fmaf(xv[i], wv[j], acc[i][j]);
    }
    __syncthreads();
  }

  float bias[6];
#pragma unroll
  for (int j = 0; j < 6; ++j) bias[j] = b1[c0 + j];
  float psum[6], pssq[6];
#pragma unroll
  for (int j = 0; j < 6; ++j) { psum[j] = 0.f; pssq[j] = 0.f; }
#pragma unroll
  for (int i = 0; i < 4; ++i) {
#pragma unroll
    for (int j = 0; j < 6; ++j) {
      float v = acc[i][j] + bias[j];
      acc[i][j] = v;
      psum[j] += v;
      pssq[j] += v * v;
    }
  }
#pragma unroll
  for (int j = 0; j < 6; ++j) {
    red[0][tr][c0 + j] = psum[j];
    red[1][tr][c0 + j] = pssq[j];
  }
#pragma unroll
  for (int i = 0; i < 4; ++i) {
    size_t base = (size_t)(rowbase + r0 + i) * F1 + c0;
    *(float2*)&h1[base]     = make_float2(acc[i][0], acc[i][1]);
    *(float2*)&h1[base + 2] = make_float2(acc[i][2], acc[i][3]);
    *(float2*)&h1[base + 4] = make_float2(acc[i][4], acc[i][5]);
  }
  __syncthreads();
  if (t < F1) {
    float s = 0.f, q = 0.f;
#pragma unroll
    for (int i = 0; i < 32; ++i) { s += red[0][i][t]; q += red[1][i][t]; }
    atomicAdd(&fsum[t], s);
    atomicAdd(&fssq[t], q);
  }
}

// ---------------- finalize BN stats + analytic global noise stats ----------------
__global__ void k_finalize(int F, float invN, float Ntot,
    const float* __restrict__ fsum, const float* __restrict__ fssq,
    const float* __restrict__ gamma, const float* __restrict__ beta,
    float* __restrict__ mu, float* __restrict__ rstd, float* __restrict__ scal,
    float u) {
  const int t = threadIdx.x;  // 64 threads, one wave
  float cm = 0.f, cs = 0.f;
  if (t < F) {
    float m = fsum[t] * invN;
    float v = fssq[t] * invN - m * m;
    float r = rsqrtf(v + 1e-5f);
    mu[t] = m; rstd[t] = r;
    float g = gamma[t], b = beta[t];
    cm = b;
    cs = g * g * r * r * v + b * b;
  }
#pragma unroll
  for (int off = 32; off > 0; off >>= 1) {
    cm += __shfl_down(cm, off, 64);
    cs += __shfl_down(cs, off, 64);
  }
  if (t == 0) {
    float m = cm / (float)F;                 // global mean of BN output
    float SS = 65536.f * cs;                 // sum of squares of BN output
    float s2 = (SS - Ntot * m * m) / (Ntot - 1.f); // ddof=1
    scal[0] = m;
    scal[1] = sqrtf(s2) * u;                 // s * U(1,2)
  }
}

// ---------------- Kernel C: BN1+noise+ReLU -> GEMM2 -> stats2 ----------------
__global__ __launch_bounds__(256) void k_layer2(
    const float* __restrict__ h1, const float* __restrict__ w2,
    const float* __restrict__ b2, const float* __restrict__ gamma1,
    const float* __restrict__ beta1, const float* __restrict__ mu,
    const float* __restrict__ rstd, const float* __restrict__ scal,
    float* __restrict__ h2, float* __restrict__ fsum2, float* __restrict__ fssq2,
    uint32_t kna, uint32_t knb) {
  __shared__ float a1s[64][49];
  __shared__ float w2s[48][25];
  __shared__ float h2s[64][25];
  __shared__ float bnp[4][48];

  const int t = threadIdx.x;
  const int rowbase = blockIdx.x * 64;
  if (t < F1) {
    bnp[0][t] = mu[t]; bnp[1][t] = rstd[t];
    bnp[2][t] = gamma1[t]; bnp[3][t] = beta1[t];
  }
  for (int e = t; e < F2 * 48; e += 256) {
    int c = e / 48, k = e - c * 48;
    w2s[k][c] = w2[e];
  }
  const float m1 = scal[0], su1 = scal[1];
  __syncthreads();

  // stage a1 = relu(BN(h1) + noise)
  const int rr = t >> 2;
  const int cc0 = (t & 3) * 12;
  const int grow = rowbase + rr;
  const float* hrow = h1 + (size_t)grow * F1 + cc0;
#pragma unroll
  for (int jj = 0; jj < 12; jj += 4) {
    float4 hv = *(const float4*)(hrow + jj);
    float vv[4] = {hv.x, hv.y, hv.z, hv.w};
#pragma unroll
    for (int q = 0; q < 4; ++q) {
      int c = cc0 + jj + q;
      float bn = (vv[q] - bnp[0][c]) * bnp[1][c] * bnp[2][c] + bnp[3][c];
      uint32_t ctr = (uint32_t)grow * 48u + (uint32_t)c;
      float nz = noise_normal(kna, knb, ctr);
      float val = bn + fmaf(su1, nz, m1);
      a1s[rr][c] = fmaxf(val, 0.f);
    }
  }
  __syncthreads();

  // GEMM2: 64 rows x 24 cols, K = 48
  const int rr2 = t & 63;
  const int c0 = (t >> 6) * 6;
  float acc[6] = {0.f, 0.f, 0.f, 0.f, 0.f, 0.f};
#pragma unroll
  for (int k = 0; k < 48; ++k) {
    float a = a1s[rr2][k];
#pragma unroll
    for (int j = 0; j < 6; ++j)
      acc[j] = fmaf(a, w2s[k][c0 + j], acc[j]);
  }
#pragma unroll
  for (int j = 0; j < 6; ++j)
    h2s[rr2][c0 + j] = acc[j] + b2[c0 + j];
  __syncthreads();

  for (int e = t; e < 64 * F2; e += 256) {
    int r2 = e / 24, c2 = e - r2 * 24;
    h2[(size_t)rowbase * F2 + e] = h2s[r2][c2];
  }
  if (t < F2) {
    float s = 0.f, q = 0.f;
    for (int r2 = 0; r2 < 64; ++r2) {
      float v = h2s[r2][t];
      s += v; q += v * v;
    }
    atomicAdd(&fsum2[t], s);
    atomicAdd(&fssq2[t], q);
  }
}

// ---------------- Kernel E: BN2+noise+ReLU -> GEMM3 -> out ----------------
__global__ __launch_bounds__(256) void k_layer3(
    const float* __restrict__ h2, const float* __restrict__ w3,
    const float* __restrict__ b3, const float* __restrict__ gamma2,
    const float* __restrict__ beta2, const float* __restrict__ mu,
    const float* __restrict__ rstd, const float* __restrict__ scal,
    float* __restrict__ out, uint32_t kna, uint32_t knb) {
  __shared__ float a2s[64][25];
  __shared__ float w3s[24][10];
  __shared__ float bnp[4][24];

  const int t = threadIdx.x;
  const int rowbase = blockIdx.x * 64;
  if (t < F2) {
    bnp[0][t] = mu[t]; bnp[1][t] = rstd[t];
    bnp[2][t] = gamma2[t]; bnp[3][t] = beta2[t];
  }
  if (t < F3 * F2) {   // 240
    int c = t / 24, k = t - c * 24;
    w3s[k][c] = w3[t];
  }
  const float m2 = scal[0], su2 = scal[1];
  __syncthreads();

  for (int e = t; e < 64 * F2; e += 256) {
    int r = e / 24, c = e - r * 24;
    float v = h2[(size_t)rowbase * F2 + e];
    float bn = (v - bnp[0][c]) * bnp[1][c] * bnp[2][c] + bnp[3][c];
    uint32_t ctr = (uint32_t)(rowbase * F2 + e);
    float nz = noise_normal(kna, knb, ctr);
    float val = bn + fmaf(su2, nz, m2);
    a2s[r][c] = fmaxf(val, 0.f);
  }
  __syncthreads();

  if (t < 128) {
    const int rr = t & 63;
    const int c0 = (t >> 6) * 5;   // 0 or 5
    float acc[5] = {0.f, 0.f, 0.f, 0.f, 0.f};
#pragma unroll
    for (int k = 0; k < 24; ++k) {
      float a = a2s[rr][k];
#pragma unroll
      for (int j = 0; j < 5; ++j)
        acc[j] = fmaf(a, w3s[k][c0 + j], acc[j]);
    }
    size_t ob = (size_t)(rowbase + rr) * F3 + c0;
#pragma unroll
    for (int j = 0; j < 5; ++j) out[ob + j] = acc[j] + b3[c0 + j];
  }
}

// ---------------- host threefry (same constants every call) ----------------
static void host_tf(uint32_t k0, uint32_t k1, uint32_t c0, uint32_t c1,
                    uint32_t& o0, uint32_t& o1) {
  uint32_t ks2 = k0 ^ k1 ^ 0x1BD11BDAu;
  uint32_t x0 = c0 + k0, x1 = c1 + k1;
  auto R = [&](int r) { x0 += x1; x1 = (x1 << r) | (x1 >> (32 - r)); x1 ^= x0; };
  R(13); R(15); R(26); R(6);  x0 += k1;  x1 += ks2 + 1u;
  R(17); R(29); R(16); R(24); x0 += ks2; x1 += k0 + 2u;
  R(13); R(15); R(26); R(6);  x0 += k0;  x1 += k1 + 3u;
  R(17); R(29); R(16); R(24); x0 += k1;  x1 += ks2 + 4u;
  R(13); R(15); R(26); R(6);  x0 += ks2; x1 += k0 + 5u;
  o0 = x0; o1 = x1;
}

static float host_uniform12(uint32_t seed) {
  // ku = first key of foldlike split(key(seed)); u = uniform(ku, (), 1.0, 2.0)
  uint32_t ka, kb, t0, t1;
  host_tf(0u, seed, 0u, 0u, ka, kb);     // foldlike split, ctr 0 -> ku
  host_tf(ka, kb, 0u, 0u, t0, t1);       // random_bits of shape ()
  uint32_t bits = t0 ^ t1;               // partitionable: XOR of both words
  uint32_t fb = (bits >> 9) | 0x3f800000u;
  float f;
  std::memcpy(&f, &fb, 4);
  return f;                               // == (f-1)*1 + 1
}

extern "C" void kernel_launch(void* const* d_in, const int* in_sizes, int n_in,
                              void* d_out, int out_size, void* d_ws, size_t ws_size,
                              hipStream_t stream) {
  (void)in_sizes; (void)n_in; (void)out_size; (void)ws_size;
  const float* x      = (const float*)d_in[0];
  const float* w1     = (const float*)d_in[1];
  const float* b1     = (const float*)d_in[2];
  const float* gamma1 = (const float*)d_in[3];
  const float* beta1  = (const float*)d_in[4];
  const float* w2     = (const float*)d_in[5];
  const float* b2     = (const float*)d_in[6];
  const float* gamma2 = (const float*)d_in[7];
  const float* beta2  = (const float*)d_in[8];
  const float* w3     = (const float*)d_in[9];
  const float* b3     = (const float*)d_in[10];
  float* out = (float*)d_out;

  float* h1 = (float*)d_ws;                       // 65536*48
  float* h2 = h1 + (size_t)MROWS * F1;            // 65536*24
  float* st = h2 + (size_t)MROWS * F2;            // stats block (1024 floats)

  // PRNG constants (deterministic, recomputed every call)
  uint32_t kn1a, kn1b, kn2a, kn2b;
  host_tf(0u, 1234u, 0u, 1u, kn1a, kn1b);         // kn of foldlike split(key(1234))
  host_tf(0u, 5678u, 0u, 1u, kn2a, kn2b);         // kn of foldlike split(key(5678))
  float u1 = host_uniform12(1234u);
  float u2 = host_uniform12(5678u);

  hipMemsetAsync(st, 0, 4096, stream);

  k_gemm1<<<MROWS / 128, 256, 0, stream>>>(x, w1, b1, h1, st + 0, st + 48);
  k_finalize<<<1, 64, 0, stream>>>(F1, 1.f / 65536.f, 65536.f * (float)F1,
                                   st + 0, st + 48, gamma1, beta1,
                                   st + 96, st + 144, st + 192, u1);
  k_layer2<<<MROWS / 64, 256, 0, stream>>>(h1, w2, b2, gamma1, beta1,
                                           st + 96, st + 144, st + 192,
                                           h2, st + 256, st + 280, kn1a, kn1b);
  k_finalize<<<1, 64, 0, stream>>>(F2, 1.f / 65536.f, 65536.f * (float)F2,
                                   st + 256, st + 280, gamma2, beta2,
                                   st + 304, st + 328, st + 352, u2);
  k_layer3<<<MROWS / 64, 256, 0, stream>>>(h2, w3, b3, gamma2, beta2,
                                           st + 304, st + 328, st + 352,
                                           out, kn2a, kn2b);
}

// Round 3
// 374.453 us; speedup vs baseline: 1.0011x; 1.0011x over previous
//
#include <hip/hip_runtime.h>
#include <cstdint>
#include <cstring>

// ---------------------------------------------------------------------------
// LinearBNNoise: x[65536,784] -> Linear(784,48) -> BN -> +noise(key 1234) -> ReLU
//                -> Linear(48,24) -> BN -> +noise(key 5678) -> ReLU -> Linear(24,10)
// GEMM1 now uses MFMA bf16 16x16x32 (HBM-bound: 205 MB x read ~ 33 us floor).
// Noise reproduces JAX threefry2x32 partitionable mode (bits = x0 ^ x1).
// ---------------------------------------------------------------------------

constexpr int MROWS = 65536;
constexpr int KDIM  = 784;
constexpr int KPAD  = 800;   // 25 * 32, zero-padded bf16 weights
constexpr int F1 = 48, F2 = 24, F3 = 10;

using frag_ab = __attribute__((ext_vector_type(8))) short;  // 8 bf16 (4 VGPRs)
using frag_cd = __attribute__((ext_vector_type(4))) float;  // 4 fp32

union UB { uint4 u; frag_ab f; };

// ---------------- threefry2x32 (20 rounds) ----------------
__device__ __forceinline__ uint32_t rotl32(uint32_t v, int r) {
  return (v << r) | (v >> (32 - r));
}

// XOR of both output words of threefry2x32(key=(k0,k1), counts=(0, ctr))
__device__ __forceinline__ uint32_t tf_mix(uint32_t k0, uint32_t k1, uint32_t ctr) {
  uint32_t ks2 = k0 ^ k1 ^ 0x1BD11BDAu;
  uint32_t x0 = k0;
  uint32_t x1 = ctr + k1;
#define TFR(r) { x0 += x1; x1 = rotl32(x1, r); x1 ^= x0; }
  TFR(13) TFR(15) TFR(26) TFR(6)
  x0 += k1;  x1 += ks2 + 1u;
  TFR(17) TFR(29) TFR(16) TFR(24)
  x0 += ks2; x1 += k0 + 2u;
  TFR(13) TFR(15) TFR(26) TFR(6)
  x0 += k0;  x1 += k1 + 3u;
  TFR(17) TFR(29) TFR(16) TFR(24)
  x0 += k1;  x1 += ks2 + 4u;
  TFR(13) TFR(15) TFR(26) TFR(6)
  x0 += ks2; x1 += k0 + 5u;
#undef TFR
  return x0 ^ x1;
}

// XLA ErfInv f32 (Giles) — exact coefficients
__device__ __forceinline__ float erfinv_f32(float x) {
  float w = -log1pf(-x * x);
  float p;
  if (w < 5.0f) {
    w = w - 2.5f;
    p = 2.81022636e-08f;
    p = fmaf(p, w, 3.43273939e-07f);
    p = fmaf(p, w, -3.5233877e-06f);
    p = fmaf(p, w, -4.39150654e-06f);
    p = fmaf(p, w, 0.00021858087f);
    p = fmaf(p, w, -0.00125372503f);
    p = fmaf(p, w, -0.00417768164f);
    p = fmaf(p, w, 0.246640727f);
    p = fmaf(p, w, 1.50140941f);
  } else {
    w = sqrtf(w) - 3.0f;
    p = -0.000200214257f;
    p = fmaf(p, w, 0.000100950558f);
    p = fmaf(p, w, 0.00134934322f);
    p = fmaf(p, w, -0.00367342844f);
    p = fmaf(p, w, 0.00573950773f);
    p = fmaf(p, w, -0.0076224613f);
    p = fmaf(p, w, 0.00943887047f);
    p = fmaf(p, w, 1.00167406f);
    p = fmaf(p, w, 2.83297682f);
  }
  return p * x;
}

__device__ __forceinline__ float noise_normal(uint32_t k0, uint32_t k1, uint32_t ctr) {
  uint32_t bits = tf_mix(k0, k1, ctr);
  float f = __uint_as_float((bits >> 9) | 0x3f800000u) - 1.0f; // [0,1)
  const float lo = -0.99999994f;
  float u = fmaxf(lo, f * 2.0f + lo);
  return 1.41421356f * erfinv_f32(u);
}

// pack two fp32 -> two bf16 (RNE) into one uint32 (low = a)
__device__ __forceinline__ uint32_t pkbf(float a, float b) {
  uint32_t ua = __float_as_uint(a); ua += 0x7fffu + ((ua >> 16) & 1u);
  uint32_t ub = __float_as_uint(b); ub += 0x7fffu + ((ub >> 16) & 1u);
  return (ua >> 16) | (ub & 0xffff0000u);
}

// ---------------- prep: w1 fp32 [48,784] -> bf16 [48,800] zero-padded ----------
__global__ void k_prep(const float* __restrict__ w1, ushort* __restrict__ wb1) {
  int i = blockIdx.x * 256 + threadIdx.x;
  if (i >= F1 * KPAD) return;
  int n = i / KPAD, k = i - n * KPAD;
  float v = (k < KDIM) ? w1[n * KDIM + k] : 0.f;
  uint32_t u = __float_as_uint(v);
  u += 0x7fffu + ((u >> 16) & 1u);
  wb1[i] = (ushort)(u >> 16);
}

// ---------------- Kernel A: MFMA bf16 GEMM1 + per-feature stats ----------------
// Block: 256 thr = 4 waves, tile 128 rows x 48 cols. Wave w: rows w*32..w*32+31
// (2 row-tiles of 16) x 3 col-tiles of 16. K loop: 25 steps of 32 (zero-pad tail).
__global__ __launch_bounds__(256) void k_gemm1(
    const float* __restrict__ x, const ushort* __restrict__ wb1,
    const float* __restrict__ b1, float* __restrict__ h1,
    float* __restrict__ fsum, float* __restrict__ fssq) {
  __shared__ __align__(16) float xs[128][36];   // stride 36: bank-uniform
  __shared__ float reds[4][48], redq[4][48];

  const int t = threadIdx.x;
  const int w = t >> 6;
  const int l = t & 63;
  const int lane16 = l & 15;
  const int quad = l >> 4;
  const int rowbase = blockIdx.x * 128;
  const int m0 = w * 32;

  frag_cd acc[2][3];
#pragma unroll
  for (int rt = 0; rt < 2; ++rt)
#pragma unroll
    for (int ct = 0; ct < 3; ++ct)
#pragma unroll
      for (int r = 0; r < 4; ++r) acc[rt][ct][r] = 0.f;

  // staging: thread t loads 16 fp32 (row t>>1, half (t&1)*16) per 32-k step
  const int srow = t >> 1;
  const int shalf = (t & 1) * 16;
  const float* xrow = x + (size_t)(rowbase + srow) * KDIM;

  // B: lane's column n = ct*16 + lane16, 8 contiguous k at quad*8
  const ushort* bptr[3];
#pragma unroll
  for (int ct = 0; ct < 3; ++ct)
    bptr[ct] = wb1 + (size_t)(ct * 16 + lane16) * KPAD + quad * 8;

  float4 xr[4];
#pragma unroll
  for (int i = 0; i < 4; ++i) xr[i] = *(const float4*)(xrow + shalf + i * 4);
  uint4 bld[3];
#pragma unroll
  for (int ct = 0; ct < 3; ++ct) bld[ct] = *(const uint4*)(bptr[ct]);

  for (int s = 0; s < 25; ++s) {
#pragma unroll
    for (int i = 0; i < 4; ++i)
      *(float4*)&xs[srow][shalf + i * 4] = xr[i];
    __syncthreads();

    const int kn = (s + 1) * 32;
    if (s < 24) {
      const bool ok = (kn + shalf + 16 <= KDIM);  // tail: upper half -> zeros
#pragma unroll
      for (int i = 0; i < 4; ++i)
        xr[i] = ok ? *(const float4*)(xrow + kn + shalf + i * 4)
                   : make_float4(0.f, 0.f, 0.f, 0.f);
    }
    uint4 bcur[3];
#pragma unroll
    for (int ct = 0; ct < 3; ++ct) bcur[ct] = bld[ct];
    if (s < 24) {
#pragma unroll
      for (int ct = 0; ct < 3; ++ct) bld[ct] = *(const uint4*)(bptr[ct] + kn);
    }

#pragma unroll
    for (int rt = 0; rt < 2; ++rt) {
      const float* ap = &xs[m0 + rt * 16 + lane16][quad * 8];
      float4 p0 = *(const float4*)ap;
      float4 p1 = *(const float4*)(ap + 4);
      UB a;
      a.u.x = pkbf(p0.x, p0.y);
      a.u.y = pkbf(p0.z, p0.w);
      a.u.z = pkbf(p1.x, p1.y);
      a.u.w = pkbf(p1.z, p1.w);
#pragma unroll
      for (int ct = 0; ct < 3; ++ct) {
        UB b; b.u = bcur[ct];
        acc[rt][ct] = __builtin_amdgcn_mfma_f32_16x16x32_bf16(
            a.f, b.f, acc[rt][ct], 0, 0, 0);
      }
    }
    __syncthreads();
  }

  // epilogue: bias, store h1, per-feature sum/ssq
  float bias[3];
#pragma unroll
  for (int ct = 0; ct < 3; ++ct) bias[ct] = b1[ct * 16 + lane16];
  float psum[3] = {0.f, 0.f, 0.f}, pssq[3] = {0.f, 0.f, 0.f};
#pragma unroll
  for (int rt = 0; rt < 2; ++rt) {
#pragma unroll
    for (int r = 0; r < 4; ++r) {
      const int grow = rowbase + m0 + rt * 16 + quad * 4 + r;
#pragma unroll
      for (int ct = 0; ct < 3; ++ct) {
        float v = acc[rt][ct][r] + bias[ct];
        h1[(size_t)grow * F1 + ct * 16 + lane16] = v;
        psum[ct] += v;
        pssq[ct] += v * v;
      }
    }
  }
#pragma unroll
  for (int ct = 0; ct < 3; ++ct) {
    psum[ct] += __shfl_xor(psum[ct], 16, 64);
    psum[ct] += __shfl_xor(psum[ct], 32, 64);
    pssq[ct] += __shfl_xor(pssq[ct], 16, 64);
    pssq[ct] += __shfl_xor(pssq[ct], 32, 64);
  }
  if (quad == 0) {
#pragma unroll
    for (int ct = 0; ct < 3; ++ct) {
      reds[w][ct * 16 + lane16] = psum[ct];
      redq[w][ct * 16 + lane16] = pssq[ct];
    }
  }
  __syncthreads();
  if (t < F1) {
    float s = reds[0][t] + reds[1][t] + reds[2][t] + reds[3][t];
    float q = redq[0][t] + redq[1][t] + redq[2][t] + redq[3][t];
    atomicAdd(&fsum[t], s);
    atomicAdd(&fssq[t], q);
  }
}

// ---------------- finalize BN stats + analytic global noise stats ----------------
__global__ void k_finalize(int F, float invN, float Ntot,
    const float* __restrict__ fsum, const float* __restrict__ fssq,
    const float* __restrict__ gamma, const float* __restrict__ beta,
    float* __restrict__ mu, float* __restrict__ rstd, float* __restrict__ scal,
    float u) {
  const int t = threadIdx.x;  // 64 threads, one wave
  float cm = 0.f, cs = 0.f;
  if (t < F) {
    float m = fsum[t] * invN;
    float v = fssq[t] * invN - m * m;
    float r = rsqrtf(v + 1e-5f);
    mu[t] = m; rstd[t] = r;
    float g = gamma[t], b = beta[t];
    cm = b;
    cs = g * g * r * r * v + b * b;
  }
#pragma unroll
  for (int off = 32; off > 0; off >>= 1) {
    cm += __shfl_down(cm, off, 64);
    cs += __shfl_down(cs, off, 64);
  }
  if (t == 0) {
    float m = cm / (float)F;
    float SS = 65536.f * cs;
    float s2 = (SS - Ntot * m * m) / (Ntot - 1.f); // ddof=1
    scal[0] = m;
    scal[1] = sqrtf(s2) * u;
  }
}

// ---------------- Kernel C: BN1+noise+ReLU -> GEMM2 -> stats2 ----------------
__global__ __launch_bounds__(256) void k_layer2(
    const float* __restrict__ h1, const float* __restrict__ w2,
    const float* __restrict__ b2, const float* __restrict__ gamma1,
    const float* __restrict__ beta1, const float* __restrict__ mu,
    const float* __restrict__ rstd, const float* __restrict__ scal,
    float* __restrict__ h2, float* __restrict__ fsum2, float* __restrict__ fssq2,
    uint32_t kna, uint32_t knb) {
  __shared__ float a1s[64][49];
  __shared__ float w2s[48][25];
  __shared__ float h2s[64][25];
  __shared__ float bnp[4][48];

  const int t = threadIdx.x;
  const int rowbase = blockIdx.x * 64;
  if (t < F1) {
    bnp[0][t] = mu[t]; bnp[1][t] = rstd[t];
    bnp[2][t] = gamma1[t]; bnp[3][t] = beta1[t];
  }
  for (int e = t; e < F2 * 48; e += 256) {
    int c = e / 48, k = e - c * 48;
    w2s[k][c] = w2[e];
  }
  const float m1 = scal[0], su1 = scal[1];
  __syncthreads();

  const int rr = t >> 2;
  const int cc0 = (t & 3) * 12;
  const int grow = rowbase + rr;
  const float* hrow = h1 + (size_t)grow * F1 + cc0;
#pragma unroll
  for (int jj = 0; jj < 12; jj += 4) {
    float4 hv = *(const float4*)(hrow + jj);
    float vv[4] = {hv.x, hv.y, hv.z, hv.w};
#pragma unroll
    for (int q = 0; q < 4; ++q) {
      int c = cc0 + jj + q;
      float bn = (vv[q] - bnp[0][c]) * bnp[1][c] * bnp[2][c] + bnp[3][c];
      uint32_t ctr = (uint32_t)grow * 48u + (uint32_t)c;
      float nz = noise_normal(kna, knb, ctr);
      float val = bn + fmaf(su1, nz, m1);
      a1s[rr][c] = fmaxf(val, 0.f);
    }
  }
  __syncthreads();

  const int rr2 = t & 63;
  const int c0 = (t >> 6) * 6;
  float acc[6] = {0.f, 0.f, 0.f, 0.f, 0.f, 0.f};
#pragma unroll
  for (int k = 0; k < 48; ++k) {
    float a = a1s[rr2][k];
#pragma unroll
    for (int j = 0; j < 6; ++j)
      acc[j] = fmaf(a, w2s[k][c0 + j], acc[j]);
  }
#pragma unroll
  for (int j = 0; j < 6; ++j)
    h2s[rr2][c0 + j] = acc[j] + b2[c0 + j];
  __syncthreads();

  for (int e = t; e < 64 * F2; e += 256) {
    int r2 = e / 24, c2 = e - r2 * 24;
    h2[(size_t)rowbase * F2 + e] = h2s[r2][c2];
  }
  if (t < F2) {
    float s = 0.f, q = 0.f;
    for (int r2 = 0; r2 < 64; ++r2) {
      float v = h2s[r2][t];
      s += v; q += v * v;
    }
    atomicAdd(&fsum2[t], s);
    atomicAdd(&fssq2[t], q);
  }
}

// ---------------- Kernel E: BN2+noise+ReLU -> GEMM3 -> out ----------------
__global__ __launch_bounds__(256) void k_layer3(
    const float* __restrict__ h2, const float* __restrict__ w3,
    const float* __restrict__ b3, const float* __restrict__ gamma2,
    const float* __restrict__ beta2, const float* __restrict__ mu,
    const float* __restrict__ rstd, const float* __restrict__ scal,
    float* __restrict__ out, uint32_t kna, uint32_t knb) {
  __shared__ float a2s[64][25];
  __shared__ float w3s[24][10];
  __shared__ float bnp[4][24];

  const int t = threadIdx.x;
  const int rowbase = blockIdx.x * 64;
  if (t < F2) {
    bnp[0][t] = mu[t]; bnp[1][t] = rstd[t];
    bnp[2][t] = gamma2[t]; bnp[3][t] = beta2[t];
  }
  if (t < F3 * F2) {
    int c = t / 24, k = t - c * 24;
    w3s[k][c] = w3[t];
  }
  const float m2 = scal[0], su2 = scal[1];
  __syncthreads();

  for (int e = t; e < 64 * F2; e += 256) {
    int r = e / 24, c = e - r * 24;
    float v = h2[(size_t)rowbase * F2 + e];
    float bn = (v - bnp[0][c]) * bnp[1][c] * bnp[2][c] + bnp[3][c];
    uint32_t ctr = (uint32_t)(rowbase * F2 + e);
    float nz = noise_normal(kna, knb, ctr);
    float val = bn + fmaf(su2, nz, m2);
    a2s[r][c] = fmaxf(val, 0.f);
  }
  __syncthreads();

  if (t < 128) {
    const int rr = t & 63;
    const int c0 = (t >> 6) * 5;
    float acc[5] = {0.f, 0.f, 0.f, 0.f, 0.f};
#pragma unroll
    for (int k = 0; k < 24; ++k) {
      float a = a2s[rr][k];
#pragma unroll
      for (int j = 0; j < 5; ++j)
        acc[j] = fmaf(a, w3s[k][c0 + j], acc[j]);
    }
    size_t ob = (size_t)(rowbase + rr) * F3 + c0;
#pragma unroll
    for (int j = 0; j < 5; ++j) out[ob + j] = acc[j] + b3[c0 + j];
  }
}

// ---------------- host threefry ----------------
static void host_tf(uint32_t k0, uint32_t k1, uint32_t c0, uint32_t c1,
                    uint32_t& o0, uint32_t& o1) {
  uint32_t ks2 = k0 ^ k1 ^ 0x1BD11BDAu;
  uint32_t x0 = c0 + k0, x1 = c1 + k1;
  auto R = [&](int r) { x0 += x1; x1 = (x1 << r) | (x1 >> (32 - r)); x1 ^= x0; };
  R(13); R(15); R(26); R(6);  x0 += k1;  x1 += ks2 + 1u;
  R(17); R(29); R(16); R(24); x0 += ks2; x1 += k0 + 2u;
  R(13); R(15); R(26); R(6);  x0 += k0;  x1 += k1 + 3u;
  R(17); R(29); R(16); R(24); x0 += k1;  x1 += ks2 + 4u;
  R(13); R(15); R(26); R(6);  x0 += ks2; x1 += k0 + 5u;
  o0 = x0; o1 = x1;
}

static float host_uniform12(uint32_t seed) {
  uint32_t ka, kb, t0, t1;
  host_tf(0u, seed, 0u, 0u, ka, kb);     // foldlike split, ctr 0 -> ku
  host_tf(ka, kb, 0u, 0u, t0, t1);       // random_bits of shape ()
  uint32_t bits = t0 ^ t1;               // partitionable: XOR of both words
  uint32_t fb = (bits >> 9) | 0x3f800000u;
  float f;
  std::memcpy(&f, &fb, 4);
  return f;
}

extern "C" void kernel_launch(void* const* d_in, const int* in_sizes, int n_in,
                              void* d_out, int out_size, void* d_ws, size_t ws_size,
                              hipStream_t stream) {
  (void)in_sizes; (void)n_in; (void)out_size; (void)ws_size;
  const float* x      = (const float*)d_in[0];
  const float* w1     = (const float*)d_in[1];
  const float* b1     = (const float*)d_in[2];
  const float* gamma1 = (const float*)d_in[3];
  const float* beta1  = (const float*)d_in[4];
  const float* w2     = (const float*)d_in[5];
  const float* b2     = (const float*)d_in[6];
  const float* gamma2 = (const float*)d_in[7];
  const float* beta2  = (const float*)d_in[8];
  const float* w3     = (const float*)d_in[9];
  const float* b3     = (const float*)d_in[10];
  float* out = (float*)d_out;

  float* h1 = (float*)d_ws;                       // 65536*48
  float* h2 = h1 + (size_t)MROWS * F1;            // 65536*24
  float* st = h2 + (size_t)MROWS * F2;            // stats block (1024 floats)
  ushort* wb1 = (ushort*)(st + 1024);             // 48*800 bf16

  uint32_t kn1a, kn1b, kn2a, kn2b;
  host_tf(0u, 1234u, 0u, 1u, kn1a, kn1b);         // kn of foldlike split(key(1234))
  host_tf(0u, 5678u, 0u, 1u, kn2a, kn2b);         // kn of foldlike split(key(5678))
  float u1 = host_uniform12(1234u);
  float u2 = host_uniform12(5678u);

  hipMemsetAsync(st, 0, 4096, stream);

  k_prep<<<(F1 * KPAD + 255) / 256, 256, 0, stream>>>(w1, wb1);
  k_gemm1<<<MROWS / 128, 256, 0, stream>>>(x, wb1, b1, h1, st + 0, st + 48);
  k_finalize<<<1, 64, 0, stream>>>(F1, 1.f / 65536.f, 65536.f * (float)F1,
                                   st + 0, st + 48, gamma1, beta1,
                                   st + 96, st + 144, st + 192, u1);
  k_layer2<<<MROWS / 64, 256, 0, stream>>>(h1, w2, b2, gamma1, beta1,
                                           st + 96, st + 144, st + 192,
                                           h2, st + 256, st + 280, kn1a, kn1b);
  k_finalize<<<1, 64, 0, stream>>>(F2, 1.f / 65536.f, 65536.f * (float)F2,
                                   st + 256, st + 280, gamma2, beta2,
                                   st + 304, st + 328, st + 352, u2);
  k_layer3<<<MROWS / 64, 256, 0, stream>>>(h2, w3, b3, gamma2, beta2,
                                           st + 304, st + 328, st + 352,
                                           out, kn2a, kn2b);
}